// Round 1
// 1707.783 us; speedup vs baseline: 1.1034x; 1.1034x over previous
//
#include <hip/hip_runtime.h>
#include <stdint.h>

// Problem constants
#define M_ROWS 8192    // B*S = 4*2048
#define N_OUT  11008
#define K_IN   4096
#define RANK   192

typedef __attribute__((ext_vector_type(8))) short bf16x8;   // 8 bf16 = 4 VGPRs
typedef __attribute__((ext_vector_type(4))) float f32x4;

// async global->LDS, 16B per lane. LDS dst = wave-uniform base + lane*16.
#define GLDS16(g, l) __builtin_amdgcn_global_load_lds( \
    (const __attribute__((address_space(1))) unsigned int*)(g), \
    (__attribute__((address_space(3))) unsigned int*)(l), 16, 0, 0)

// RTNE float -> bf16 bits (matches __float2bfloat16 for finite values)
static __device__ __forceinline__ unsigned short f2bf(float f) {
    union { float f; unsigned int u; } a; a.f = f;
    unsigned int u = a.u;
    u += 0x7fffu + ((u >> 16) & 1u);
    return (unsigned short)(u >> 16);
}

// ---------------------------------------------------------------------------
// Pass 1: wq = weight + Bd @ Bu  (f32), plus per-(row, colblock) min/max.
// Tile: 64 rows x 256 cols, K=192. 256 thr = 32(tx) x 8(ty); 8x8 per thread.
// grid (11008/64=172, 4096/256=16)
// ---------------------------------------------------------------------------
__global__ __launch_bounds__(256) void k_delta_minmax(
    const float* __restrict__ Wg, const float* __restrict__ Bd,
    const float* __restrict__ Bu, float* __restrict__ wq,
    float* __restrict__ pmin, float* __restrict__ pmax)
{
    __shared__ float bdT[RANK][68];   // transposed Bd tile, pad 64->68
    __shared__ float buS[8][256];     // Bu K-chunk
    const int t  = threadIdx.x;
    const int tx = t & 31, ty = t >> 5;
    const int row0 = blockIdx.x * 64;
    const int col0 = blockIdx.y * 256;

    for (int i = t; i < 64 * RANK; i += 256) {
        int r = i / RANK, k = i - r * RANK;
        bdT[k][r] = Bd[(size_t)(row0 + r) * RANK + k];
    }

    float acc[8][8];
#pragma unroll
    for (int a = 0; a < 8; ++a)
#pragma unroll
        for (int b = 0; b < 8; ++b) acc[a][b] = 0.0f;

    for (int kc = 0; kc < RANK / 8; ++kc) {
        __syncthreads();
#pragma unroll
        for (int j = 0; j < 8; ++j)
            buS[j][t] = Bu[(size_t)(kc * 8 + j) * K_IN + col0 + t];
        __syncthreads();
#pragma unroll
        for (int k = 0; k < 8; ++k) {
            float bd[8], bu[8];
#pragma unroll
            for (int rr = 0; rr < 8; ++rr) bd[rr] = bdT[kc * 8 + k][ty * 8 + rr];
#pragma unroll
            for (int cc = 0; cc < 8; ++cc) bu[cc] = buS[k][tx + 32 * cc];
#pragma unroll
            for (int rr = 0; rr < 8; ++rr)
#pragma unroll
                for (int cc = 0; cc < 8; ++cc)
                    acc[rr][cc] = fmaf(bd[rr], bu[cc], acc[rr][cc]);
        }
    }

    float rmin[8], rmax[8];
#pragma unroll
    for (int rr = 0; rr < 8; ++rr) { rmin[rr] = 3.0e38f; rmax[rr] = -3.0e38f; }
#pragma unroll
    for (int rr = 0; rr < 8; ++rr) {
        size_t gr = (size_t)(row0 + ty * 8 + rr);
#pragma unroll
        for (int cc = 0; cc < 8; ++cc) {
            size_t gc = (size_t)(col0 + tx + 32 * cc);
            float w = Wg[gr * K_IN + gc] + acc[rr][cc];
            wq[gr * K_IN + gc] = w;
            rmin[rr] = fminf(rmin[rr], w);
            rmax[rr] = fmaxf(rmax[rr], w);
        }
    }
#pragma unroll
    for (int off = 16; off >= 1; off >>= 1) {
#pragma unroll
        for (int rr = 0; rr < 8; ++rr) {
            rmin[rr] = fminf(rmin[rr], __shfl_xor(rmin[rr], off, 64));
            rmax[rr] = fmaxf(rmax[rr], __shfl_xor(rmax[rr], off, 64));
        }
    }
    if (tx == 0) {
#pragma unroll
        for (int rr = 0; rr < 8; ++rr) {
            int gr = row0 + ty * 8 + rr;
            pmin[(size_t)gr * 16 + blockIdx.y] = rmin[rr];
            pmax[(size_t)gr * 16 + blockIdx.y] = rmax[rr];
        }
    }
}

// ---------------------------------------------------------------------------
// Pass 2: per-row scale / zero-point.
// ---------------------------------------------------------------------------
__global__ __launch_bounds__(256) void k_scale_zero(
    const float* __restrict__ pmin, const float* __restrict__ pmax,
    float* __restrict__ scale, float* __restrict__ zero)
{
    int r = blockIdx.x * 256 + threadIdx.x;
    if (r >= N_OUT) return;
    float mn = 0.0f, mx = 0.0f;
#pragma unroll
    for (int i = 0; i < 16; ++i) {
        mn = fminf(mn, pmin[(size_t)r * 16 + i]);
        mx = fmaxf(mx, pmax[(size_t)r * 16 + i]);
    }
    float s = fmaxf((mx - mn) / 15.0f, 1e-8f);
    scale[r] = s;
    zero[r] = rintf(-mn / s);
}

// ---------------------------------------------------------------------------
// Pass 3: fake-quant + cast to bf16.  4 elems/thread, exact grid.
// ---------------------------------------------------------------------------
__global__ __launch_bounds__(256) void k_quant_cast(
    const float* __restrict__ wq, const float* __restrict__ scale,
    const float* __restrict__ zero, unsigned short* __restrict__ wb)
{
    size_t i = ((size_t)blockIdx.x * 256 + threadIdx.x) * 4;
    int r = (int)(i >> 12);
    float s = scale[r], z = zero[r];
    float4 v = *(const float4*)(wq + i);
    float in[4] = {v.x, v.y, v.z, v.w};
    unsigned short h[4];
#pragma unroll
    for (int j = 0; j < 4; ++j) {
        float q = rintf(in[j] / s) + z;
        q = fminf(fmaxf(q, 0.0f), 15.0f);
        h[j] = f2bf((q - z) * s);
    }
    unsigned int lo = (unsigned int)h[0] | ((unsigned int)h[1] << 16);
    unsigned int hi = (unsigned int)h[2] | ((unsigned int)h[3] << 16);
    *(unsigned long long*)(wb + i) = ((unsigned long long)hi << 32) | lo;
}

// ---------------------------------------------------------------------------
// Pass 4: x -> bf16.
// ---------------------------------------------------------------------------
__global__ __launch_bounds__(256) void k_cast_x(
    const float* __restrict__ x, unsigned short* __restrict__ xb)
{
    size_t i = ((size_t)blockIdx.x * 256 + threadIdx.x) * 4;
    float4 v = *(const float4*)(x + i);
    unsigned int lo = (unsigned int)f2bf(v.x) | ((unsigned int)f2bf(v.y) << 16);
    unsigned int hi = (unsigned int)f2bf(v.z) | ((unsigned int)f2bf(v.w) << 16);
    *(unsigned long long*)(xb + i) = ((unsigned long long)hi << 32) | lo;
}

// ---------------------------------------------------------------------------
// Pass 5: C[m,n] = sum_k A[m,k]*W[n,k] + bias[n]
// 256x256 tile, BK=64, 8 waves (2M x 4N), 512 thr, 128 KiB LDS.
// 8-phase (4 quadrant-phases/tile) schedule: raw s_barrier + counted vmcnt(6),
// st_16x32 XOR swizzle (pre-swizzled global src, swizzled ds_read),
// s_setprio around MFMA clusters, bijective XCD blockIdx swizzle.
//
// LDS per buffer d (65536 B): A at +0, B at +32768.
//   operand = [half h: rows h*128..h*128+127][panel ks: k 32*ks..+31][128][64B]
//   half = 16 KiB contiguous; panel = 8 KiB.
//   swizzle: within-panel byte p -> p ^ (((p>>9)&1)<<5)  (row bit3 flips 32B col)
// Quadrant order (mh,nh): (0,0),(0,1),(1,1),(1,0).
//   LDS-read deaths: Q0 -> A-h0, B-h0 (B reg-reused at Q3); Q1 -> B-h1; Q2 -> A-h1
//   Stage slots: Q0: (t+1).B-h0 [other buf]; Q1: (t+2).A-h0; Q2: (t+2).B-h1;
//                Q3: (t+2).A-h1 then vmcnt(6)  (leaves exactly the 3 (t+2) halves
//                in flight; guarantees all 4 (t+1) halves landed).
// grid (8192/256=32, 11008/256=43) = 1376 = 8*172 (bijective XCD swizzle ok)
// ---------------------------------------------------------------------------
#define NT (K_IN / 64)   // 64 K-tiles

__global__ __launch_bounds__(512, 2) void k_gemm(
    const unsigned short* __restrict__ A,   // bf16 bits [M_ROWS][K_IN]
    const unsigned short* __restrict__ W,   // bf16 bits [N_OUT][K_IN]
    const float* __restrict__ bias,
    float* __restrict__ C)                  // [M_ROWS][N_OUT]
{
    extern __shared__ char lds[];           // 131072 B

    const int tid  = threadIdx.x;
    const int lane = tid & 63;
    const int w    = tid >> 6;              // wave 0..7
    const int wr   = w >> 2;                // 0..1 (M half of tile)
    const int wn   = w & 3;                 // 0..3 (N quarter within nh-half)

    // bijective XCD swizzle: 1376 blocks = 8 XCDs x 172
    const int orig = blockIdx.y * gridDim.x + blockIdx.x;
    const int swz  = (orig & 7) * 172 + (orig >> 3);
    const int bm0  = (swz & 31) << 8;       // gridDim.x = 32 (M)
    const int bn0  = (swz >> 5) << 8;       // 0..42 (N)

    // fragment-read lane geometry (identical per-lane data to m97 structure)
    const int lrow = lane & 15, lq = lane >> 4;
    const int colA = (lq * 16) ^ (((lrow >> 3) & 1) << 5);  // swizzled col bytes

    // staging lane geometry: linear LDS dest, inverse(=same)-swizzled global src
    const int srow = w * 16 + (lane >> 2);                       // 0..127
    const int scol = ((lane & 3) * 8) ^ (((lane >> 5) & 1) * 16); // elems 0..31

    const unsigned short* pa = A + (size_t)(bm0 + srow) * K_IN + scol;
    const unsigned short* pw = W + (size_t)(bn0 + srow) * K_IN + scol;
    char* ldsw = lds + w * 1024;            // wave-uniform; HW adds lane*16

    // frag-read bases (byte addrs into lds)
    char* abase = lds + (wr * 64 + lrow) * 64 + colA;
    char* bbase = lds + 32768 + (wn * 32 + lrow) * 64 + colA;

// stage one 16 KiB half (2 panels) of tile KT into buffer D
#define STAGE_A(D, KT, H) { \
    const unsigned short* s_ = pa + (size_t)((H) * 128) * K_IN + (KT) * 64; \
    char* l_ = ldsw + (D) * 65536 + (H) * 16384; \
    GLDS16(s_,      l_); \
    GLDS16(s_ + 32, l_ + 8192); }
#define STAGE_B(D, KT, H) { \
    const unsigned short* s_ = pw + (size_t)((H) * 128) * K_IN + (KT) * 64; \
    char* l_ = ldsw + (D) * 65536 + 32768 + (H) * 16384; \
    GLDS16(s_,      l_); \
    GLDS16(s_ + 32, l_ + 8192); }

#define READ_A(D, MH) { \
    _Pragma("unroll") for (int mi = 0; mi < 4; ++mi) { \
        af[mi][0] = *(const bf16x8*)(abase + (D) * 65536 + (MH) * 16384 + mi * 1024); \
        af[mi][1] = *(const bf16x8*)(abase + (D) * 65536 + (MH) * 16384 + 8192 + mi * 1024); } }
#define READ_B(D, NH, B_) { \
    _Pragma("unroll") for (int ni = 0; ni < 2; ++ni) { \
        B_[ni][0] = *(const bf16x8*)(bbase + (D) * 65536 + (NH) * 16384 + ni * 1024); \
        B_[ni][1] = *(const bf16x8*)(bbase + (D) * 65536 + (NH) * 16384 + 8192 + ni * 1024); } }

#define MFMA_Q(MH, NH, B_) { \
    __builtin_amdgcn_s_setprio(1); \
    _Pragma("unroll") for (int mi = 0; mi < 4; ++mi) \
    _Pragma("unroll") for (int ni = 0; ni < 2; ++ni) { \
        acc[MH][NH][mi][ni] = __builtin_amdgcn_mfma_f32_16x16x32_bf16( \
            af[mi][0], B_[ni][0], acc[MH][NH][mi][ni], 0, 0, 0); \
        acc[MH][NH][mi][ni] = __builtin_amdgcn_mfma_f32_16x16x32_bf16( \
            af[mi][1], B_[ni][1], acc[MH][NH][mi][ni], 0, 0, 0); } \
    __builtin_amdgcn_s_setprio(0); }

    f32x4 acc[2][2][4][2] = {};             // 128 VGPRs
    bf16x8 af[4][2], b0[2][2], b1[2][2];

    // prologue: tile0 all 4 halves, then tile1's Q1/Q2/Q3-slot halves (3)
    STAGE_A(0, 0, 0); STAGE_A(0, 0, 1); STAGE_B(0, 0, 0); STAGE_B(0, 0, 1);
    STAGE_A(1, 1, 0); STAGE_B(1, 1, 1); STAGE_A(1, 1, 1);
    asm volatile("s_waitcnt vmcnt(6)" ::: "memory");   // tile0 fully landed
    __builtin_amdgcn_s_barrier();

#define TILE_BODY(T, D, DN) { \
    /* Q0 (mh0,nh0) */ \
    READ_A(D, 0); READ_B(D, 0, b0); \
    if ((T) + 1 < NT) STAGE_B(DN, (T) + 1, 0); \
    __builtin_amdgcn_s_barrier(); \
    MFMA_Q(0, 0, b0); \
    __builtin_amdgcn_s_barrier(); \
    /* Q1 (mh0,nh1) */ \
    READ_B(D, 1, b1); \
    if ((T) + 2 < NT) STAGE_A(D, (T) + 2, 0); \
    __builtin_amdgcn_s_barrier(); \
    MFMA_Q(0, 1, b1); \
    __builtin_amdgcn_s_barrier(); \
    /* Q2 (mh1,nh1) */ \
    READ_A(D, 1); \
    if ((T) + 2 < NT) STAGE_B(D, (T) + 2, 1); \
    __builtin_amdgcn_s_barrier(); \
    MFMA_Q(1, 1, b1); \
    __builtin_amdgcn_s_barrier(); \
    /* Q3 (mh1,nh0) */ \
    if ((T) + 2 < NT) { \
        STAGE_A(D, (T) + 2, 1); \
        asm volatile("s_waitcnt vmcnt(6)" ::: "memory"); \
    } else { \
        asm volatile("s_waitcnt vmcnt(0)" ::: "memory"); \
    } \
    __builtin_amdgcn_s_barrier(); \
    MFMA_Q(1, 0, b0); \
    __builtin_amdgcn_s_barrier(); }

#pragma unroll 1
    for (int tt = 0; tt < NT; tt += 2) {
        TILE_BODY(tt,     0, 1);
        TILE_BODY(tt + 1, 1, 0);
    }

    // epilogue: C/D layout col = lane&15, row = (lane>>4)*4 + reg
#pragma unroll
    for (int mh = 0; mh < 2; ++mh)
#pragma unroll
    for (int mi = 0; mi < 4; ++mi) {
        const int row = bm0 + mh * 128 + wr * 64 + mi * 16 + lq * 4;
#pragma unroll
        for (int nh = 0; nh < 2; ++nh)
#pragma unroll
        for (int ni = 0; ni < 2; ++ni) {
            const int col = bn0 + nh * 128 + wn * 32 + ni * 16 + lrow;
            const float bb = bias[col];
            const f32x4 v = acc[mh][nh][mi][ni];
#pragma unroll
            for (int r = 0; r < 4; ++r)
                C[(size_t)(row + r) * N_OUT + col] = v[r] + bb;
        }
    }
}

// ---------------------------------------------------------------------------
extern "C" void kernel_launch(void* const* d_in, const int* in_sizes, int n_in,
                              void* d_out, int out_size, void* d_ws, size_t ws_size,
                              hipStream_t stream)
{
    const float* x      = (const float*)d_in[0];   // [4,2048,4096]
    const float* weight = (const float*)d_in[1];   // [11008,4096]
    const float* Bd     = (const float*)d_in[2];   // [11008,192]
    const float* Bu     = (const float*)d_in[3];   // [192,4096]
    const float* bias   = (const float*)d_in[4];   // [11008]
    float* out = (float*)d_out;                    // [8192,11008] f32

    char* ws = (char*)d_ws;
    float*          wq    = (float*)(ws);                      // 180,355,072 B
    float*          pmin  = (float*)(ws + 180355072);          //     704,512 B
    float*          pmax  = (float*)(ws + 181059584);          //     704,512 B
    float*          scale = (float*)(ws + 181764096);          //      44,032 B
    float*          zero  = (float*)(ws + 181808128);          //      44,032 B
    unsigned short* wb    = (unsigned short*)(ws + 181852160); //  90,177,536 B
    unsigned short* xb    = (unsigned short*)(ws + 272029696); //  67,108,864 B

    static bool attr_set = false;
    if (!attr_set) {
        hipFuncSetAttribute((const void*)k_gemm,
                            hipFuncAttributeMaxDynamicSharedMemorySize, 131072);
        attr_set = true;
    }

    k_delta_minmax<<<dim3(N_OUT / 64, K_IN / 256), 256, 0, stream>>>(
        weight, Bd, Bu, wq, pmin, pmax);
    k_scale_zero<<<(N_OUT + 255) / 256, 256, 0, stream>>>(pmin, pmax, scale, zero);
    k_quant_cast<<<(N_OUT * (K_IN / 4)) / 256, 256, 0, stream>>>(wq, scale, zero, wb);
    k_cast_x<<<(M_ROWS * (K_IN / 4)) / 256, 256, 0, stream>>>(x, xb);
    k_gemm<<<dim3(M_ROWS / 256, N_OUT / 256), 512, 131072, stream>>>(xb, wb, bias, out);
}